// Round 9
// baseline (1152.763 us; speedup 1.0000x reference)
//
#include <hip/hip_runtime.h>
#include <hip/hip_bf16.h>
#include <string.h>

// Problem constants
#define B_ 64
#define T_ 256
#define F_ 64
#define U_ 512
#define G4_ 2048     // 4*U
#define KTOT 576     // F + U
#define KSTEPS 18    // KTOT/32

typedef __attribute__((ext_vector_type(8))) short short8;
typedef __attribute__((ext_vector_type(4))) float v4f;
typedef __attribute__((ext_vector_type(4))) int i4;
typedef unsigned short u16;

__device__ __forceinline__ float bf2f(u16 b) {
    unsigned int x = ((unsigned int)b) << 16;
    float f; memcpy(&f, &x, 4); return f;
}
__device__ __forceinline__ u16 f2bf(float f) {
    __hip_bfloat16 h = __float2bfloat16(f);
    u16 b; memcpy(&b, &h, 2); return b;
}
__device__ __forceinline__ float sigmoidf_(float x) { return 1.f / (1.f + __expf(-x)); }
__device__ __forceinline__ float tanhf_(float x) {   // clamped exp form (R8/R9-proven)
    float xc = fminf(15.f, fmaxf(-15.f, x));
    float e = __expf(2.f * xc);
    return (e - 1.f) / (e + 1.f);
}

// Dtype-flexible element load: fg=1 -> fp32, fg=0 -> bf16.
__device__ __forceinline__ float ldany(const void* p, size_t i, int fg) {
    return fg ? ((const float*)p)[i] : bf2f(((const u16*)p)[i]);
}

// Workspace layout (bytes; offsets 64-aligned) -- unchanged.
#define WS_FLAG   0             // int dtype-flag @0
#define WS_XB     64            // bf16 [T][B][F]          2,097,152
#define WS_WP     2097216       // bf16 packed weights     2,359,296
#define WS_H2     4456512       // bf16 [2][B][U]            131,072
#define WS_DOT    4718656       // fp32 [B][T]                65,536
#define WS_BIASF  4784192       // fp32 [4U]                   8,192
#define WS_ATTWF  4792384       // fp32 [T][T]               262,144
#define WS_ATTBF  5054528       // fp32 [T]                    1,024
#define WS_OUTWF  5055552       // fp32 [U]                    2,048
#define WS_OUTBF  5057600       // fp32 [1]                       64
#define WS_NEED   5057920

// ---------------------------------------------------------------------------
// Kernel 0: dtype detection (flag: 1 = fp32 inputs, 0 = bf16).
// ---------------------------------------------------------------------------
__global__ __launch_bounds__(256) void detect(const unsigned int* __restrict__ w,
                                              int* __restrict__ flag) {
    __shared__ int votes;
    if (threadIdx.x == 0) votes = 0;
    __syncthreads();
    unsigned int v = w[threadIdx.x];
    int e = (v >> 7) & 0xFF;
    if (e >= 100 && e <= 135) atomicAdd(&votes, 1);
    __syncthreads();
    if (threadIdx.x == 0) *flag = (votes < 200) ? 1 : 0;
}

// ---------------------------------------------------------------------------
// Kernel 1: canonicalize inputs.  x -> xb bf16 [T][B][F]; small arrays ->
// fp32; dot -> 0; h2 ping-pong -> 0 (tag 0 == stale for every expected tag;
// zeros are also the correct h_{-1} at t=0 where the check is skipped).
// ---------------------------------------------------------------------------
__global__ __launch_bounds__(256) void convert(const void* __restrict__ x,
                                               const void* __restrict__ bias,
                                               const void* __restrict__ attW,
                                               const void* __restrict__ attb,
                                               const void* __restrict__ outW,
                                               const void* __restrict__ outb,
                                               const int* __restrict__ flag,
                                               u16* __restrict__ xb,
                                               float* __restrict__ biasf,
                                               float* __restrict__ attWf,
                                               float* __restrict__ attbf,
                                               float* __restrict__ outWf,
                                               float* __restrict__ outbf,
                                               float* __restrict__ dot,
                                               unsigned int* __restrict__ h2z) {
    int fg = *flag;
    size_t i = (size_t)blockIdx.x * 256 + threadIdx.x;
    if (i < 1048576) {
        float v = ldany(x, i, fg);
        int b = (int)(i >> 14), t = (int)((i >> 6) & 255), f = (int)(i & 63);
        xb[((size_t)t * B_ + b) * F_ + f] = f2bf(v);
        return;
    }
    i -= 1048576;
    if (i < 2048)  { biasf[i] = ldany(bias, i, fg); return; }
    i -= 2048;
    if (i < 65536) { attWf[i] = ldany(attW, i, fg); return; }
    i -= 65536;
    if (i < 256)   { attbf[i] = ldany(attb, i, fg); return; }
    i -= 256;
    if (i < 512)   { outWf[i] = ldany(outW, i, fg); return; }
    i -= 512;
    if (i < 1)     { outbf[i] = ldany(outb, i, fg); return; }
    i -= 1;
    if (i < 16384) { dot[i] = 0.f; return; }
    i -= 16384;
    if (i < 32768) { h2z[i] = 0u; return; }   // both h ping-pong buffers
}

// ---------------------------------------------------------------------------
// Kernel 2: pack [kernel; rec_kernel] into MFMA-B fragments, cols c'=4u+gate.
// Lane l of fragment (nt, ks) supplies B[k=ks*32+(l>>4)*8+j][col=nt*16+(l&15)].
// ---------------------------------------------------------------------------
__global__ __launch_bounds__(256) void pack_w(const void* __restrict__ kin,
                                              const void* __restrict__ krec,
                                              const int* __restrict__ flag,
                                              u16* __restrict__ Wp) {
    int fg = *flag;
    int gid = blockIdx.x * 256 + threadIdx.x;   // grid = 576*256 == 128*18*64
    int lane = gid & 63;
    int frag = gid >> 6;
    int nt = frag / KSTEPS;
    int ks = frag - nt * KSTEPS;
    int kbase = ks * 32 + (lane >> 4) * 8;
    int cp = nt * 16 + (lane & 15);
    int u = cp >> 2, gate = cp & 3;
    int C = gate * U_ + u;
    short8 v;
    for (int j = 0; j < 8; j++) {
        int k = kbase + j;
        float w = (k < F_) ? ldany(kin, (size_t)k * G4_ + C, fg)
                           : ldany(krec, (size_t)(k - F_) * G4_ + C, fg);
        v[j] = (short)f2bf(w);
    }
    *reinterpret_cast<short8*>(Wp + (size_t)gid * 8) = v;
}

// ---------------------------------------------------------------------------
// Kernel 3: PERSISTENT LSTM -- R20: TWO INDEPENDENT ROW-GROUP RECURRENCES
// TIME-MULTIPLEXED PER BLOCK (latency hiding by independent stream).
//
// Evidence chain: R18 tail shaves null; R19 clique shrink (traffic and
// straggler degree halved) REGRESSED via doubled serial work -> the cost is
// the exposed store->visibility->poll RT, re-polled ~300cyc after our own
// store.  Fix: 32 blocks = (pair p=bid&1 -> rgA=2p, rgB=2p+1) x 16 gu.
// Each step: phase A (full R15 step for rgA) then phase B (for rgB).  The
// store(rgA,t)->poll(rgA,t+1) gap now contains ALL of phase B (~1200+cyc):
// if visibility fits, polls accept FIRST TRY.  Per-rg-step serial work
// unchanged (18 MFMAs, R15 epilogue); W is shared between phases (depends
// only on the unit tile) so VGPRs don't double.  Protocol per rg is
// byte-identical R15 (poll asm, tags, stores, barriers).  Degrades
// gracefully to R15 behavior if visibility exceeds the gap.
// ---------------------------------------------------------------------------
__global__ __launch_bounds__(512, 1) void lstm_persist(const u16* __restrict__ xb,
                                                       const float* __restrict__ biasf,
                                                       const float* __restrict__ outWf,
                                                       const u16* __restrict__ Wp,
                                                       u16* __restrict__ h2,
                                                       float* __restrict__ dot) {
    __shared__ __align__(16) u16 stageA[16 * 520];  // rgA: 16 rows x 512 h (+8 pad)
    __shared__ __align__(16) u16 stageB[16 * 520];  // rgB
    __shared__ float dpA[32][16][9];                // rgA dot partials (+pad)
    __shared__ float dpB[32][16][9];                // rgB

    int tid = threadIdx.x;
    int bid = blockIdx.x;
    int p = bid & 1;                      // row-group pair selector
    int rgA = 2 * p;                      // rows [32p, 32p+16)
    int rgB = 2 * p + 1;                  // rows [32p+16, 32p+32)
    int gu = bid >> 1;                    // unit-group: units [32gu, 32gu+32)
    int w = tid >> 6, l = tid & 63;
    int nt = gu * 8 + w;                  // this wave's global n-tile (shared by A/B)

    // Weights into VGPRs: 18 fragments, loaded once, shared by both phases.
    short8 W[KSTEPS];
    #pragma unroll
    for (int ks = 0; ks < KSTEPS; ks++)
        W[ks] = *reinterpret_cast<const short8*>(Wp + ((size_t)(nt * KSTEPS + ks) * 64 + l) * 8);

    // MFMA roles.
    int arowA = rgA * 16 + (l & 15);      // A row, phase A (global batch index)
    int arowB = rgB * 16 + (l & 15);      // A row, phase B
    int koff = (l >> 4) * 8;              // k-chunk within a 32-wide ks
    // Poll/stage roles: wave w handles local rows 2w, 2w+1 (per rg).
    int plr = 2 * w + (l >> 5);           // local row polled by this lane
    int pcol = (l & 31) * 16;             // u16 column of this lane's 32B chunk
    size_t poffA = (size_t)(rgA * 16 + plr) * U_ + pcol;
    size_t poffB = (size_t)(rgB * 16 + plr) * U_ + pcol;
    // Post-transpose elementwise roles: lane owns (row erow, unit 4nt+j).
    int e = l & 3;                        // row-within-quad after transpose
    int erow = 4 * (l >> 4) + e;          // local row 0..15
    int unit = 4 * nt + ((l >> 2) & 3);   // global unit
    // Per-lane column bias (col cp = nt*16 + (l&15); biasf is gate-major).
    int cp = nt * 16 + (l & 15);
    float bc = biasf[(cp & 3) * U_ + (cp >> 2)];
    float wout = outWf[unit];
    float cA = 0.f, cB = 0.f;             // independent cell states

    for (int t = 0; t < T_; t++) {
        u16* hcur = h2 + (size_t)(t & 1) * (B_ * U_);
        const u16* hprev = h2 + (size_t)((t + 1) & 1) * (B_ * U_);
        unsigned int wtag = ((unsigned)(t >> 1) & 1u) ^ 1u;
        unsigned int rpat = ((((unsigned)(t - 1) >> 1) & 1u) ^ 1u) * 0x00010001u;

        // ================= Phase A: row-group rgA =================
        {
            const u16* xrow = xb + ((size_t)t * B_ + arowA) * F_;
            short8 a0 = *reinterpret_cast<const short8*>(xrow + koff);
            short8 a1 = *reinterpret_cast<const short8*>(xrow + 32 + koff);
            v4f accP = {bc, bc, bc, bc};
            v4f accQ = {0.f, 0.f, 0.f, 0.f};
            accP = __builtin_amdgcn_mfma_f32_16x16x32_bf16(a0, W[0], accP, 0, 0, 0);
            accQ = __builtin_amdgcn_mfma_f32_16x16x32_bf16(a1, W[1], accQ, 0, 0, 0);
            __builtin_amdgcn_sched_barrier(0);

            // R15-proven poll (single asm: loads + vmcnt(0) fused).
            i4 q0, q1;
            {
                const void* bp = (const void*)(hprev + poffA);
                int spins = 0;
                for (;;) {
                    asm volatile(
                        "global_load_dwordx4 %0, %2, off sc0 sc1\n\t"
                        "global_load_dwordx4 %1, %2, off offset:16 sc0 sc1\n\t"
                        "s_waitcnt vmcnt(0)"
                        : "=v"(q0), "=v"(q1) : "v"(bp) : "memory");
                    if (t == 0) break;
                    unsigned bad = 0;
                    bad |= (((unsigned)q0[0]) ^ rpat) & 0x00010001u;
                    bad |= (((unsigned)q0[1]) ^ rpat) & 0x00010001u;
                    bad |= (((unsigned)q0[2]) ^ rpat) & 0x00010001u;
                    bad |= (((unsigned)q0[3]) ^ rpat) & 0x00010001u;
                    bad |= (((unsigned)q1[0]) ^ rpat) & 0x00010001u;
                    bad |= (((unsigned)q1[1]) ^ rpat) & 0x00010001u;
                    bad |= (((unsigned)q1[2]) ^ rpat) & 0x00010001u;
                    bad |= (((unsigned)q1[3]) ^ rpat) & 0x00010001u;
                    if (__ballot(bad == 0) == ~0ull) break;
                    if (++spins > (1 << 14)) break;
                    __builtin_amdgcn_s_sleep(2);
                }
            }
            *reinterpret_cast<i4*>(&stageA[plr * 520 + pcol])     = q0;
            *reinterpret_cast<i4*>(&stageA[plr * 520 + pcol + 8]) = q1;
            __syncthreads();   // stage-A ready

            #pragma unroll
            for (int ks = 2; ks < KSTEPS; ks += 2) {
                short8 ah0 = *reinterpret_cast<const short8*>(
                    &stageA[(l & 15) * 520 + (ks - 2) * 32 + koff]);
                short8 ah1 = *reinterpret_cast<const short8*>(
                    &stageA[(l & 15) * 520 + (ks - 1) * 32 + koff]);
                accP = __builtin_amdgcn_mfma_f32_16x16x32_bf16(ah0, W[ks],     accP, 0, 0, 0);
                accQ = __builtin_amdgcn_mfma_f32_16x16x32_bf16(ah1, W[ks + 1], accQ, 0, 0, 0);
            }
            v4f acc = accP + accQ;

            // Verified 4x4 lane/reg transpose: final(lane e, reg p) = orig(lane p, reg e).
            float g0 = acc[0], g1 = acc[1], g2 = acc[2], g3 = acc[3];
            {
                float t0 = __shfl_xor(g1, 1, 64);
                float t1 = __shfl_xor(g0, 1, 64);
                float t2 = __shfl_xor(g3, 1, 64);
                float t3 = __shfl_xor(g2, 1, 64);
                float b0 = ((0 ^ e) & 1) ? t0 : g0;
                float b1 = ((1 ^ e) & 1) ? t1 : g1;
                float b2 = ((2 ^ e) & 1) ? t2 : g2;
                float b3 = ((3 ^ e) & 1) ? t3 : g3;
                float u0 = __shfl_xor(b2, 2, 64);
                float u1 = __shfl_xor(b3, 2, 64);
                float u2 = __shfl_xor(b0, 2, 64);
                float u3 = __shfl_xor(b1, 2, 64);
                g0 = ((0 ^ e) & 2) ? u0 : b0;
                g1 = ((1 ^ e) & 2) ? u1 : b1;
                g2 = ((2 ^ e) & 2) ? u2 : b2;
                g3 = ((3 ^ e) & 2) ? u3 : b3;
            }
            float ig = sigmoidf_(g0);
            float fg = sigmoidf_(g1);
            float gc = tanhf_(g2);
            float og = sigmoidf_(g3);
            cA = fg * cA + ig * gc;
            float h = og * tanhf_(cA);

            float hp = __shfl_xor(h, 4, 64);
            if (((l >> 2) & 1) == 0) {
                unsigned int pk = (unsigned int)(((unsigned)f2bf(h)  & 0xFFFEu) | wtag)
                                | ((unsigned int)(((unsigned)f2bf(hp) & 0xFFFEu) | wtag) << 16);
                void* sp = (void*)(hcur + (size_t)(rgA * 16 + erow) * U_ + unit);
                asm volatile("global_store_dword %0, %1, off sc0 sc1"
                             :: "v"(sp), "v"(pk) : "memory");
            }

            float s = h * wout;
            s += __shfl_xor(s, 4, 64);
            s += __shfl_xor(s, 8, 64);
            if ((l & 12) == 0) dpA[t & 31][erow][w] = s;
        }

        // ================= Phase B: row-group rgB =================
        {
            const u16* xrow = xb + ((size_t)t * B_ + arowB) * F_;
            short8 a0 = *reinterpret_cast<const short8*>(xrow + koff);
            short8 a1 = *reinterpret_cast<const short8*>(xrow + 32 + koff);
            v4f accP = {bc, bc, bc, bc};
            v4f accQ = {0.f, 0.f, 0.f, 0.f};
            accP = __builtin_amdgcn_mfma_f32_16x16x32_bf16(a0, W[0], accP, 0, 0, 0);
            accQ = __builtin_amdgcn_mfma_f32_16x16x32_bf16(a1, W[1], accQ, 0, 0, 0);
            __builtin_amdgcn_sched_barrier(0);

            i4 q0, q1;
            {
                const void* bp = (const void*)(hprev + poffB);
                int spins = 0;
                for (;;) {
                    asm volatile(
                        "global_load_dwordx4 %0, %2, off sc0 sc1\n\t"
                        "global_load_dwordx4 %1, %2, off offset:16 sc0 sc1\n\t"
                        "s_waitcnt vmcnt(0)"
                        : "=v"(q0), "=v"(q1) : "v"(bp) : "memory");
                    if (t == 0) break;
                    unsigned bad = 0;
                    bad |= (((unsigned)q0[0]) ^ rpat) & 0x00010001u;
                    bad |= (((unsigned)q0[1]) ^ rpat) & 0x00010001u;
                    bad |= (((unsigned)q0[2]) ^ rpat) & 0x00010001u;
                    bad |= (((unsigned)q0[3]) ^ rpat) & 0x00010001u;
                    bad |= (((unsigned)q1[0]) ^ rpat) & 0x00010001u;
                    bad |= (((unsigned)q1[1]) ^ rpat) & 0x00010001u;
                    bad |= (((unsigned)q1[2]) ^ rpat) & 0x00010001u;
                    bad |= (((unsigned)q1[3]) ^ rpat) & 0x00010001u;
                    if (__ballot(bad == 0) == ~0ull) break;
                    if (++spins > (1 << 14)) break;
                    __builtin_amdgcn_s_sleep(2);
                }
            }
            *reinterpret_cast<i4*>(&stageB[plr * 520 + pcol])     = q0;
            *reinterpret_cast<i4*>(&stageB[plr * 520 + pcol + 8]) = q1;
            __syncthreads();   // stage-B ready

            #pragma unroll
            for (int ks = 2; ks < KSTEPS; ks += 2) {
                short8 ah0 = *reinterpret_cast<const short8*>(
                    &stageB[(l & 15) * 520 + (ks - 2) * 32 + koff]);
                short8 ah1 = *reinterpret_cast<const short8*>(
                    &stageB[(l & 15) * 520 + (ks - 1) * 32 + koff]);
                accP = __builtin_amdgcn_mfma_f32_16x16x32_bf16(ah0, W[ks],     accP, 0, 0, 0);
                accQ = __builtin_amdgcn_mfma_f32_16x16x32_bf16(ah1, W[ks + 1], accQ, 0, 0, 0);
            }
            v4f acc = accP + accQ;

            float g0 = acc[0], g1 = acc[1], g2 = acc[2], g3 = acc[3];
            {
                float t0 = __shfl_xor(g1, 1, 64);
                float t1 = __shfl_xor(g0, 1, 64);
                float t2 = __shfl_xor(g3, 1, 64);
                float t3 = __shfl_xor(g2, 1, 64);
                float b0 = ((0 ^ e) & 1) ? t0 : g0;
                float b1 = ((1 ^ e) & 1) ? t1 : g1;
                float b2 = ((2 ^ e) & 1) ? t2 : g2;
                float b3 = ((3 ^ e) & 1) ? t3 : g3;
                float u0 = __shfl_xor(b2, 2, 64);
                float u1 = __shfl_xor(b3, 2, 64);
                float u2 = __shfl_xor(b0, 2, 64);
                float u3 = __shfl_xor(b1, 2, 64);
                g0 = ((0 ^ e) & 2) ? u0 : b0;
                g1 = ((1 ^ e) & 2) ? u1 : b1;
                g2 = ((2 ^ e) & 2) ? u2 : b2;
                g3 = ((3 ^ e) & 2) ? u3 : b3;
            }
            float ig = sigmoidf_(g0);
            float fg = sigmoidf_(g1);
            float gc = tanhf_(g2);
            float og = sigmoidf_(g3);
            cB = fg * cB + ig * gc;
            float h = og * tanhf_(cB);

            float hp = __shfl_xor(h, 4, 64);
            if (((l >> 2) & 1) == 0) {
                unsigned int pk = (unsigned int)(((unsigned)f2bf(h)  & 0xFFFEu) | wtag)
                                | ((unsigned int)(((unsigned)f2bf(hp) & 0xFFFEu) | wtag) << 16);
                void* sp = (void*)(hcur + (size_t)(rgB * 16 + erow) * U_ + unit);
                asm volatile("global_store_dword %0, %1, off sc0 sc1"
                             :: "v"(sp), "v"(pk) : "memory");
            }

            float s = h * wout;
            s += __shfl_xor(s, 4, 64);
            s += __shfl_xor(s, 8, 64);
            if ((l & 12) == 0) dpB[t & 31][erow][w] = s;
        }

        // Flush both dot-partial arrays every 32 steps (one barrier).
        // dp writes of step t precede this barrier; next writes (t+1) happen
        // only after the next stage barriers, so reads here are race-free.
        if ((t & 31) == 31) {
            __syncthreads();
            int t0_ = t - 31;
            int tt = tid >> 4, row = tid & 15;
            float sumA = 0.f, sumB = 0.f;
            #pragma unroll
            for (int ww = 0; ww < 8; ww++) {
                sumA += dpA[tt][row][ww];
                sumB += dpB[tt][row][ww];
            }
            atomicAdd(&dot[(size_t)(rgA * 16 + row) * T_ + (t0_ + tt)], sumA);
            atomicAdd(&dot[(size_t)(rgB * 16 + row) * T_ + (t0_ + tt)], sumB);
        }
    }
}

// ---------------------------------------------------------------------------
// Kernel 4: finale.  attention collapses to scalars:
//   coef_t = (t==0) ? 1 : sum_{j<t} att_W[t,j];  shift_t = (t==0) ? 0 : att_b[t]
//   out[b,t] = sigmoid(coef_t * dot[b,t] + shift_t * sum(out_W) + out_b)
// grid = 256 (one block per t).  Output dtype follows the input dtype flag.
// ---------------------------------------------------------------------------
__global__ __launch_bounds__(256) void finale(const float* __restrict__ attWf,
                                              const float* __restrict__ attbf,
                                              const float* __restrict__ outWf,
                                              const float* __restrict__ outbf,
                                              const float* __restrict__ dot,
                                              const int* __restrict__ flag,
                                              void* __restrict__ out) {
    __shared__ float red[256];
    int t = blockIdx.x, tid = threadIdx.x;
    int fg = *flag;

    float v = (tid < t) ? attWf[(size_t)t * T_ + tid] : 0.f;
    red[tid] = v; __syncthreads();
    for (int s = 128; s > 0; s >>= 1) { if (tid < s) red[tid] += red[tid + s]; __syncthreads(); }
    float coef = (t == 0) ? 1.f : red[0];
    __syncthreads();
    red[tid] = outWf[tid] + outWf[tid + 256]; __syncthreads();
    for (int s = 128; s > 0; s >>= 1) { if (tid < s) red[tid] += red[tid + s]; __syncthreads(); }
    float sumW = red[0];

    float base = ((t == 0) ? 0.f : attbf[t]) * sumW + outbf[0];

    if (tid < B_) {
        float s = sigmoidf_(coef * dot[(size_t)tid * T_ + t] + base);
        size_t idx = (size_t)tid * T_ + t;
        if (fg) ((float*)out)[idx] = s;
        else    ((u16*)out)[idx] = f2bf(s);
    }
}

// ---------------------------------------------------------------------------
extern "C" void kernel_launch(void* const* d_in, const int* in_sizes, int n_in,
                              void* d_out, int out_size, void* d_ws, size_t ws_size,
                              hipStream_t stream) {
    const void* x    = d_in[0];
    const void* kin  = d_in[1];
    const void* krec = d_in[2];
    const void* bias = d_in[3];
    const void* attW = d_in[4];
    const void* attb = d_in[5];
    const void* outW = d_in[6];
    const void* outb = d_in[7];

    if (ws_size < (size_t)WS_NEED) return;

    char* ws = (char*)d_ws;
    int*   flag  = (int*)(ws + WS_FLAG);
    u16*   xb    = (u16*)(ws + WS_XB);
    u16*   Wp    = (u16*)(ws + WS_WP);
    u16*   h2    = (u16*)(ws + WS_H2);
    float* dot   = (float*)(ws + WS_DOT);
    float* biasf = (float*)(ws + WS_BIASF);
    float* attWf = (float*)(ws + WS_ATTWF);
    float* attbf = (float*)(ws + WS_ATTBF);
    float* outWf = (float*)(ws + WS_OUTWF);
    float* outbf = (float*)(ws + WS_OUTBF);

    detect<<<1, 256, 0, stream>>>((const unsigned int*)kin, flag);
    convert<<<4556, 256, 0, stream>>>(x, bias, attW, attb, outW, outb, flag,
                                      xb, biasf, attWf, attbf, outWf, outbf, dot,
                                      (unsigned int*)h2);
    pack_w<<<576, 256, 0, stream>>>(kin, krec, flag, Wp);
    lstm_persist<<<32, 512, 0, stream>>>(xb, biasf, outWf, Wp, h2, dot);
    finale<<<256, 256, 0, stream>>>(attWf, attbf, outWf, outbf, dot, flag, d_out);
}

// Round 10
// 607.504 us; speedup vs baseline: 1.8975x; 1.8975x over previous
//
#include <hip/hip_runtime.h>
#include <hip/hip_bf16.h>
#include <string.h>

// Problem constants
#define B_ 64
#define T_ 256
#define F_ 64
#define U_ 512
#define G4_ 2048     // 4*U
#define KTOT 576     // F + U
#define KSTEPS 18    // KTOT/32

typedef __attribute__((ext_vector_type(8))) short short8;
typedef __attribute__((ext_vector_type(4))) float v4f;
typedef __attribute__((ext_vector_type(4))) int i4;
typedef unsigned short u16;

__device__ __forceinline__ float bf2f(u16 b) {
    unsigned int x = ((unsigned int)b) << 16;
    float f; memcpy(&f, &x, 4); return f;
}
__device__ __forceinline__ u16 f2bf(float f) {
    __hip_bfloat16 h = __float2bfloat16(f);
    u16 b; memcpy(&b, &h, 2); return b;
}
__device__ __forceinline__ float sigmoidf_(float x) { return 1.f / (1.f + __expf(-x)); }
__device__ __forceinline__ float tanhf_(float x) {   // clamped exp form (R8/R9-proven)
    float xc = fminf(15.f, fmaxf(-15.f, x));
    float e = __expf(2.f * xc);
    return (e - 1.f) / (e + 1.f);
}

// Dtype-flexible element load: fg=1 -> fp32, fg=0 -> bf16.
__device__ __forceinline__ float ldany(const void* p, size_t i, int fg) {
    return fg ? ((const float*)p)[i] : bf2f(((const u16*)p)[i]);
}

// Workspace layout (bytes; offsets 64-aligned) -- unchanged.
#define WS_FLAG   0             // int dtype-flag @0
#define WS_XB     64            // bf16 [T][B][F]          2,097,152
#define WS_WP     2097216       // bf16 packed weights     2,359,296
#define WS_H2     4456512       // bf16 [2][B][U]            131,072
#define WS_DOT    4718656       // fp32 [B][T]                65,536
#define WS_BIASF  4784192       // fp32 [4U]                   8,192
#define WS_ATTWF  4792384       // fp32 [T][T]               262,144
#define WS_ATTBF  5054528       // fp32 [T]                    1,024
#define WS_OUTWF  5055552       // fp32 [U]                    2,048
#define WS_OUTBF  5057600       // fp32 [1]                       64
#define WS_NEED   5057920

// ---------------------------------------------------------------------------
// Kernel 0: dtype detection (flag: 1 = fp32 inputs, 0 = bf16).
// ---------------------------------------------------------------------------
__global__ __launch_bounds__(256) void detect(const unsigned int* __restrict__ w,
                                              int* __restrict__ flag) {
    __shared__ int votes;
    if (threadIdx.x == 0) votes = 0;
    __syncthreads();
    unsigned int v = w[threadIdx.x];
    int e = (v >> 7) & 0xFF;
    if (e >= 100 && e <= 135) atomicAdd(&votes, 1);
    __syncthreads();
    if (threadIdx.x == 0) *flag = (votes < 200) ? 1 : 0;
}

// ---------------------------------------------------------------------------
// Kernel 1: canonicalize inputs.  x -> xb bf16 [T][B][F]; small arrays ->
// fp32; dot -> 0; h2 ping-pong -> 0 (tag 0 == stale for every expected tag;
// zeros are also the correct h_{-1} at t=0 where the check is skipped).
// ---------------------------------------------------------------------------
__global__ __launch_bounds__(256) void convert(const void* __restrict__ x,
                                               const void* __restrict__ bias,
                                               const void* __restrict__ attW,
                                               const void* __restrict__ attb,
                                               const void* __restrict__ outW,
                                               const void* __restrict__ outb,
                                               const int* __restrict__ flag,
                                               u16* __restrict__ xb,
                                               float* __restrict__ biasf,
                                               float* __restrict__ attWf,
                                               float* __restrict__ attbf,
                                               float* __restrict__ outWf,
                                               float* __restrict__ outbf,
                                               float* __restrict__ dot,
                                               unsigned int* __restrict__ h2z) {
    int fg = *flag;
    size_t i = (size_t)blockIdx.x * 256 + threadIdx.x;
    if (i < 1048576) {
        float v = ldany(x, i, fg);
        int b = (int)(i >> 14), t = (int)((i >> 6) & 255), f = (int)(i & 63);
        xb[((size_t)t * B_ + b) * F_ + f] = f2bf(v);
        return;
    }
    i -= 1048576;
    if (i < 2048)  { biasf[i] = ldany(bias, i, fg); return; }
    i -= 2048;
    if (i < 65536) { attWf[i] = ldany(attW, i, fg); return; }
    i -= 65536;
    if (i < 256)   { attbf[i] = ldany(attb, i, fg); return; }
    i -= 256;
    if (i < 512)   { outWf[i] = ldany(outW, i, fg); return; }
    i -= 512;
    if (i < 1)     { outbf[i] = ldany(outb, i, fg); return; }
    i -= 1;
    if (i < 16384) { dot[i] = 0.f; return; }
    i -= 16384;
    if (i < 32768) { h2z[i] = 0u; return; }   // both h ping-pong buffers
}

// ---------------------------------------------------------------------------
// Kernel 2: pack [kernel; rec_kernel] into MFMA-B fragments, cols c'=4u+gate.
// Lane l of fragment (nt, ks) supplies B[k=ks*32+(l>>4)*8+j][col=nt*16+(l&15)].
// ---------------------------------------------------------------------------
__global__ __launch_bounds__(256) void pack_w(const void* __restrict__ kin,
                                              const void* __restrict__ krec,
                                              const int* __restrict__ flag,
                                              u16* __restrict__ Wp) {
    int fg = *flag;
    int gid = blockIdx.x * 256 + threadIdx.x;   // grid = 576*256 == 128*18*64
    int lane = gid & 63;
    int frag = gid >> 6;
    int nt = frag / KSTEPS;
    int ks = frag - nt * KSTEPS;
    int kbase = ks * 32 + (lane >> 4) * 8;
    int cp = nt * 16 + (lane & 15);
    int u = cp >> 2, gate = cp & 3;
    int C = gate * U_ + u;
    short8 v;
    for (int j = 0; j < 8; j++) {
        int k = kbase + j;
        float w = (k < F_) ? ldany(kin, (size_t)k * G4_ + C, fg)
                           : ldany(krec, (size_t)(k - F_) * G4_ + C, fg);
        v[j] = (short)f2bf(w);
    }
    *reinterpret_cast<short8*>(Wp + (size_t)gid * 8) = v;
}

// ---------------------------------------------------------------------------
// Kernel 3: PERSISTENT LSTM.  R21 = R15 RESTORED VERBATIM (best verified:
// 610.34us total / 529us lstm).  The full lever ledger vs this step's
// ~4970cyc: R16 faster cadence -85%; R17/R18 tail shaves null; R19 clique
// shrink -26% (its traffic mechanisms verified in counters but time-null);
// R20 phase interleave -50% (convoy coupling through intra-block barriers;
// straggler-maxes add, not hide); R12/R13 cheaper scopes incorrect on HW.
// Exchange-free partitions: >=2304 padded MFMAs/block/step ~ 11k cyc/CU
// (>2x whole step) -> arithmetically dead.  The residual cost is the
// system-scope store->IF-visibility->poll RT + convoy jitter of a 256-step
// serial recurrence: a latency floor, not a counter roofline.
//
// Structure: one barrier/step; in-reg 4x4 D-transpose (no gbuf); x-MFMAs
// hoisted above the poll; R10-proven poll (loads + vmcnt(0) in ONE asm).
// ---------------------------------------------------------------------------
__global__ __launch_bounds__(512, 1) void lstm_persist(const u16* __restrict__ xb,
                                                       const float* __restrict__ biasf,
                                                       const float* __restrict__ outWf,
                                                       const u16* __restrict__ Wp,
                                                       u16* __restrict__ h2,
                                                       float* __restrict__ dot) {
    __shared__ __align__(16) u16 stage[16 * 520];   // 16 rows x 512 h (+8 pad)
    __shared__ float dp[32][16][9];                 // dot partials: step x row x wave(+pad)

    int tid = threadIdx.x;
    int bid = blockIdx.x;
    int rg = bid & 3;                     // row-group: rows [16rg, 16rg+16)
    int gu = bid >> 2;                    // unit-group: units [32gu, 32gu+32)
    int w = tid >> 6, l = tid & 63;
    int nt = gu * 8 + w;                  // this wave's global n-tile

    // Weights into VGPRs: 18 fragments, loaded once.
    short8 W[KSTEPS];
    #pragma unroll
    for (int ks = 0; ks < KSTEPS; ks++)
        W[ks] = *reinterpret_cast<const short8*>(Wp + ((size_t)(nt * KSTEPS + ks) * 64 + l) * 8);

    // MFMA roles.
    int arow = rg * 16 + (l & 15);        // A row (global batch index)
    int koff = (l >> 4) * 8;              // k-chunk within a 32-wide ks
    // Poll/stage roles: wave w handles local rows 2w, 2w+1.
    int plr = 2 * w + (l >> 5);           // local row polled by this lane
    int pcol = (l & 31) * 16;             // u16 column of this lane's 32B chunk
    // Post-transpose elementwise roles: lane owns (row erow, unit 4nt+j).
    int e = l & 3;                        // row-within-quad after transpose
    int j = (l >> 2) & 3;                 // unit-within-wave
    int erow = 4 * (l >> 4) + e;          // local row 0..15
    int unit = 4 * nt + j;                // global unit
    float bia = biasf[0 * U_ + unit], bif = biasf[1 * U_ + unit];
    float big = biasf[2 * U_ + unit], bio = biasf[3 * U_ + unit];
    float wout = outWf[unit];
    float c = 0.f;

    for (int t = 0; t < T_; t++) {
        u16* hcur = h2 + (size_t)(t & 1) * (B_ * U_);
        const u16* hprev = h2 + (size_t)((t + 1) & 1) * (B_ * U_);
        unsigned int wtag = ((unsigned)(t >> 1) & 1u) ^ 1u;
        unsigned int rpat = ((((unsigned)(t - 1) >> 1) & 1u) ^ 1u) * 0x00010001u;

        // x-part first: independent of h_{t-1}; runs before the poll so the
        // poll-success -> h-store path holds only h-MFMAs + elementwise.
        const u16* xrow = xb + ((size_t)t * B_ + arow) * F_;
        short8 a0 = *reinterpret_cast<const short8*>(xrow + koff);
        short8 a1 = *reinterpret_cast<const short8*>(xrow + 32 + koff);
        v4f acc0 = {0.f, 0.f, 0.f, 0.f}, acc1 = {0.f, 0.f, 0.f, 0.f};
        acc0 = __builtin_amdgcn_mfma_f32_16x16x32_bf16(a0, W[0], acc0, 0, 0, 0);
        acc1 = __builtin_amdgcn_mfma_f32_16x16x32_bf16(a1, W[1], acc1, 0, 0, 0);
        __builtin_amdgcn_sched_barrier(0);   // pin x-MFMAs before the poll

        // Poll this wave's 2 rows of h_{t-1}: 2 coherent 16B loads per lane,
        // loads + vmcnt(0) fused in ONE asm block (the only safe primitive:
        // registers are always landed when checked).  Accept when all 8
        // dwords are fresh wave-unanimously.  R10-proven, byte-identical.
        i4 q0, q1;
        {
            const void* bp = (const void*)(hprev + (size_t)(rg * 16 + plr) * U_ + pcol);
            int spins = 0;
            for (;;) {
                asm volatile(
                    "global_load_dwordx4 %0, %2, off sc0 sc1\n\t"
                    "global_load_dwordx4 %1, %2, off offset:16 sc0 sc1\n\t"
                    "s_waitcnt vmcnt(0)"
                    : "=v"(q0), "=v"(q1) : "v"(bp) : "memory");
                if (t == 0) break;        // zeros are the correct h_{-1}
                unsigned bad = 0;
                bad |= (((unsigned)q0[0]) ^ rpat) & 0x00010001u;
                bad |= (((unsigned)q0[1]) ^ rpat) & 0x00010001u;
                bad |= (((unsigned)q0[2]) ^ rpat) & 0x00010001u;
                bad |= (((unsigned)q0[3]) ^ rpat) & 0x00010001u;
                bad |= (((unsigned)q1[0]) ^ rpat) & 0x00010001u;
                bad |= (((unsigned)q1[1]) ^ rpat) & 0x00010001u;
                bad |= (((unsigned)q1[2]) ^ rpat) & 0x00010001u;
                bad |= (((unsigned)q1[3]) ^ rpat) & 0x00010001u;
                if (__ballot(bad == 0) == ~0ull) break;
                if (++spins > (1 << 14)) break;   // bailout: never hang
                __builtin_amdgcn_s_sleep(2);      // short backoff
            }
        }
        // Stage into LDS (row-major, 520-u16 stride).
        *reinterpret_cast<i4*>(&stage[plr * 520 + pcol])     = q0;
        *reinterpret_cast<i4*>(&stage[plr * 520 + pcol + 8]) = q1;
        __syncthreads();   // barrier 1: stage ready (only barrier per step)

        // h-part MFMAs from staged LDS.
        #pragma unroll
        for (int ks = 2; ks < KSTEPS; ks += 2) {
            short8 ah0 = *reinterpret_cast<const short8*>(
                &stage[(l & 15) * 520 + (ks - 2) * 32 + koff]);
            short8 ah1 = *reinterpret_cast<const short8*>(
                &stage[(l & 15) * 520 + (ks - 1) * 32 + koff]);
            acc0 = __builtin_amdgcn_mfma_f32_16x16x32_bf16(ah0, W[ks],     acc0, 0, 0, 0);
            acc1 = __builtin_amdgcn_mfma_f32_16x16x32_bf16(ah1, W[ks + 1], acc1, 0, 0, 0);
        }
        v4f acc = acc0 + acc1;

        // In-register 4x4 transpose among lane-quads (lane low2 bits):
        // before: lane (low2=g) holds rows 4h+0..3 (regs) of gate g;
        // after:  lane (low2=e) holds gates 0..3 (regs) of row 4h+e.
        // Verified: final(lane e, reg p) = orig(lane p, reg e).
        float g0 = acc[0], g1 = acc[1], g2 = acc[2], g3 = acc[3];
        {
            float t0 = __shfl_xor(g1, 1, 64);
            float t1 = __shfl_xor(g0, 1, 64);
            float t2 = __shfl_xor(g3, 1, 64);
            float t3 = __shfl_xor(g2, 1, 64);
            float b0 = ((0 ^ e) & 1) ? t0 : g0;
            float b1 = ((1 ^ e) & 1) ? t1 : g1;
            float b2 = ((2 ^ e) & 1) ? t2 : g2;
            float b3 = ((3 ^ e) & 1) ? t3 : g3;
            float u0 = __shfl_xor(b2, 2, 64);
            float u1 = __shfl_xor(b3, 2, 64);
            float u2 = __shfl_xor(b0, 2, 64);
            float u3 = __shfl_xor(b1, 2, 64);
            g0 = ((0 ^ e) & 2) ? u0 : b0;   // gate i of (row erow, unit)
            g1 = ((1 ^ e) & 2) ? u1 : b1;   // gate f
            g2 = ((2 ^ e) & 2) ? u2 : b2;   // gate c
            g3 = ((3 ^ e) & 2) ? u3 : b3;   // gate o
        }

        // Elementwise: this lane owns (row erow, unit).  No LDS, no barrier.
        {
            float ig = sigmoidf_(g0 + bia);
            float fg = sigmoidf_(g1 + bif);
            float gc = tanhf_(g2 + big);
            float og = sigmoidf_(g3 + bio);
            c = fg * c + ig * gc;
            float h = og * tanhf_(c);

            // Pack unit pair into a dword with LSB tags; even-j lane stores.
            float hp = __shfl_xor(h, 4, 64);   // partner unit+1 (lane bit2)
            if (((l >> 2) & 1) == 0) {
                unsigned int pk = (unsigned int)(((unsigned)f2bf(h)  & 0xFFFEu) | wtag)
                                | ((unsigned int)(((unsigned)f2bf(hp) & 0xFFFEu) | wtag) << 16);
                void* sp = (void*)(hcur + (size_t)(rg * 16 + erow) * U_ + unit);
                asm volatile("global_store_dword %0, %1, off sc0 sc1"
                             :: "v"(sp), "v"(pk) : "memory");
            }

            // dot partial: sum this wave's 4 units (lane bits 2-3) per row.
            float s = h * wout;
            s += __shfl_xor(s, 4, 64);
            s += __shfl_xor(s, 8, 64);
            if ((l & 12) == 0) dp[t & 31][erow][w] = s;
        }

        // Flush dot partials every 32 steps: 512 threads cover 32x16 slots,
        // summing the 8 per-wave partials.  barrier 1 of step t+1 keeps any
        // fast wave from overwriting dp slot 0 before these reads finish
        // (dp writes of step t+1 happen after that barrier).
        if ((t & 31) == 31) {
            __syncthreads();
            int t0_ = t - 31;
            int tt = tid >> 4, row = tid & 15;
            float sum = 0.f;
            #pragma unroll
            for (int ww = 0; ww < 8; ww++) sum += dp[tt][row][ww];
            atomicAdd(&dot[(size_t)(rg * 16 + row) * T_ + (t0_ + tt)], sum);
        }
    }
}

// ---------------------------------------------------------------------------
// Kernel 4: finale.  attention collapses to scalars:
//   coef_t = (t==0) ? 1 : sum_{j<t} att_W[t,j];  shift_t = (t==0) ? 0 : att_b[t]
//   out[b,t] = sigmoid(coef_t * dot[b,t] + shift_t * sum(out_W) + out_b)
// grid = 256 (one block per t).  Output dtype follows the input dtype flag.
// ---------------------------------------------------------------------------
__global__ __launch_bounds__(256) void finale(const float* __restrict__ attWf,
                                              const float* __restrict__ attbf,
                                              const float* __restrict__ outWf,
                                              const float* __restrict__ outbf,
                                              const float* __restrict__ dot,
                                              const int* __restrict__ flag,
                                              void* __restrict__ out) {
    __shared__ float red[256];
    int t = blockIdx.x, tid = threadIdx.x;
    int fg = *flag;

    float v = (tid < t) ? attWf[(size_t)t * T_ + tid] : 0.f;
    red[tid] = v; __syncthreads();
    for (int s = 128; s > 0; s >>= 1) { if (tid < s) red[tid] += red[tid + s]; __syncthreads(); }
    float coef = (t == 0) ? 1.f : red[0];
    __syncthreads();
    red[tid] = outWf[tid] + outWf[tid + 256]; __syncthreads();
    for (int s = 128; s > 0; s >>= 1) { if (tid < s) red[tid] += red[tid + s]; __syncthreads(); }
    float sumW = red[0];

    float base = ((t == 0) ? 0.f : attbf[t]) * sumW + outbf[0];

    if (tid < B_) {
        float s = sigmoidf_(coef * dot[(size_t)tid * T_ + t] + base);
        size_t idx = (size_t)tid * T_ + t;
        if (fg) ((float*)out)[idx] = s;
        else    ((u16*)out)[idx] = f2bf(s);
    }
}

// ---------------------------------------------------------------------------
extern "C" void kernel_launch(void* const* d_in, const int* in_sizes, int n_in,
                              void* d_out, int out_size, void* d_ws, size_t ws_size,
                              hipStream_t stream) {
    const void* x    = d_in[0];
    const void* kin  = d_in[1];
    const void* krec = d_in[2];
    const void* bias = d_in[3];
    const void* attW = d_in[4];
    const void* attb = d_in[5];
    const void* outW = d_in[6];
    const void* outb = d_in[7];

    if (ws_size < (size_t)WS_NEED) return;

    char* ws = (char*)d_ws;
    int*   flag  = (int*)(ws + WS_FLAG);
    u16*   xb    = (u16*)(ws + WS_XB);
    u16*   Wp    = (u16*)(ws + WS_WP);
    u16*   h2    = (u16*)(ws + WS_H2);
    float* dot   = (float*)(ws + WS_DOT);
    float* biasf = (float*)(ws + WS_BIASF);
    float* attWf = (float*)(ws + WS_ATTWF);
    float* attbf = (float*)(ws + WS_ATTBF);
    float* outWf = (float*)(ws + WS_OUTWF);
    float* outbf = (float*)(ws + WS_OUTBF);

    detect<<<1, 256, 0, stream>>>((const unsigned int*)kin, flag);
    convert<<<4556, 256, 0, stream>>>(x, bias, attW, attb, outW, outb, flag,
                                      xb, biasf, attWf, attbf, outWf, outbf, dot,
                                      (unsigned int*)h2);
    pack_w<<<576, 256, 0, stream>>>(kin, krec, flag, Wp);
    lstm_persist<<<64, 512, 0, stream>>>(xb, biasf, outWf, Wp, h2, dot);
    finale<<<256, 256, 0, stream>>>(attWf, attbf, outWf, outbf, dot, flag, d_out);
}